// Round 8
// baseline (127.445 us; speedup 1.0000x reference)
//
#include <hip/hip_runtime.h>

// Periodic radius graph: out[i][j][k] = |(frac[j]-frac[i]+off[k]) @ cell|
// masked to (d2 > 1e-12 && d < 5.0), else 0. N=1024, 27 images.
// 113.2 MB fp32 output.
//
// R8: NO LDS, NO barriers. One thread per output float4 (flat idx 4v..4v+3,
// spans at most 2 pairs since 27>4). Both candidate pairs' df computed
// unconditionally; per-element cndmask select. Stores: one coalesced
// dwordx4 per thread straight from registers.
// Rationale: R4 (VALU-50%) neutral, R5 (no barriers) neutral, R7 (persistent+
// nt stores) negative -> the untested structural element is the LDS round-trip
// itself: 27.6 KB/block caps occupancy at 5 blocks/CU and burns ~240 LDS-pipe
// cycles/wave/tile. This kernel has zero LDS -> 8 blocks/CU, deeper store
// pipelining. Math expressions verbatim from bit-exact R3 (absmax 0.0).

#define NATOMS 1024
#define NIMG 27
#define TOTAL (NATOMS * NATOMS * NIMG)   // 28,311,552
#define NVEC4 (TOTAL / 4)                // 7,077,888 = 27648 * 256

typedef float f32x4 __attribute__((ext_vector_type(4)));

__global__ __launch_bounds__(256) void PeriodicRadiusGraph_kernel(
    const float* __restrict__ frac,   // [1024, 3]
    const float* __restrict__ cell,   // [3, 3]
    float* __restrict__ out)          // [1024, 1024, 27] flat
{
    const unsigned v = blockIdx.x * 256u + threadIdx.x;  // float4 id, < NVEC4
    const unsigned u = v * 4u;                           // first flat element
    const unsigned p0 = u / 27u;                         // pair id (magic div)
    const unsigned r  = u - p0 * 27u;                    // image id 0..26
    const unsigned pmax = NATOMS * NATOMS - 1u;
    const unsigned p1 = (p0 + 1u <= pmax) ? p0 + 1u : pmax;  // clamped next pair

    // cell rows (wave-uniform -> scalar loads)
    const float c00 = cell[0], c01 = cell[1], c02 = cell[2];
    const float c10 = cell[3], c11 = cell[4], c12 = cell[5];
    const float c20 = cell[6], c21 = cell[7], c22 = cell[8];

    // pair A = p0
    const unsigned jA = p0 & (NATOMS - 1u), iA = p0 >> 10;
    const float dfAx = frac[3u * jA + 0u] - frac[3u * iA + 0u];
    const float dfAy = frac[3u * jA + 1u] - frac[3u * iA + 1u];
    const float dfAz = frac[3u * jA + 2u] - frac[3u * iA + 2u];
    // pair B = p1 (only used when the float4 crosses the 27-boundary)
    const unsigned jB = p1 & (NATOMS - 1u), iB = p1 >> 10;
    const float dfBx = frac[3u * jB + 0u] - frac[3u * iB + 0u];
    const float dfBy = frac[3u * jB + 1u] - frac[3u * iB + 1u];
    const float dfBz = frac[3u * jB + 2u] - frac[3u * iB + 2u];

    f32x4 res;
#pragma unroll
    for (int cidx = 0; cidx < 4; ++cidx) {
        const unsigned kraw = r + (unsigned)cidx;        // 0..29
        const bool second = kraw >= 27u;
        const unsigned k = second ? kraw - 27u : kraw;   // 0..26

        const float dfx = second ? dfBx : dfAx;
        const float dfy = second ? dfBy : dfAy;
        const float dfz = second ? dfBz : dfAz;

        // meshgrid(indexing="ij") order: (k/9, (k/3)%3, k%3) - 1
        const float ox = (float)((int)(k / 9u) - 1);
        const float oy = (float)((int)((k / 3u) % 3u) - 1);
        const float oz = (float)((int)(k % 3u) - 1);

        // exact same expression forms as the bit-exact R1-R5 kernels
        const float fx = dfx + ox;
        const float fy = dfy + oy;
        const float fz = dfz + oz;

        const float vx = fx * c00 + fy * c10 + fz * c20;
        const float vy = fx * c01 + fy * c11 + fz * c21;
        const float vz = fx * c02 + fy * c12 + fz * c22;

        const float d2 = vx * vx + vy * vy + vz * vz;
        const float d  = __builtin_amdgcn_sqrtf(d2);     // mask from d2: exact
        res[cidx] = (d2 > 1e-12f && d2 < 25.0f) ? d : 0.0f;
    }

    ((f32x4*)out)[v] = res;   // coalesced dwordx4, registers -> global
}

extern "C" void kernel_launch(void* const* d_in, const int* in_sizes, int n_in,
                              void* d_out, int out_size, void* d_ws, size_t ws_size,
                              hipStream_t stream) {
    const float* frac = (const float*)d_in[0];
    const float* cell = (const float*)d_in[1];
    float* out = (float*)d_out;

    const int grid = NVEC4 / 256;   // 27648 blocks, exact
    PeriodicRadiusGraph_kernel<<<grid, 256, 0, stream>>>(frac, cell, out);
}